// Round 5
// baseline (122.399 us; speedup 1.0000x reference)
//
#include <hip/hip_runtime.h>

// AtomEncoderLayer: B=4, N=32, D=128, H=8, NC=27, DK=16, DFF=512, L=864.
// fp32 tensors, int32 mask.
// Low-rank collapse: phat(b,c,n) = coords(b,c,n)·Wphat (rank-3 subspace),
// dc = coords(c,n) - coords(c,i) (relative position). Exact algebra:
//   a_row centered = xh(n) + dc·Wphat,  var = var_x + (dc^T M dc + 2 dc·dxp)/D
//   K - center = is*(Axk(n) + dc·Gk) + ek,   V analog with Axv/Gv/ev
//   att_d = (Σ_n Tn[h][n] Axv[n][d] + Σ_j RD[h][j] Gv[j][d]) / S_h + ev_d
// Two kernels: k_pre (tiny per-row prep + consts), k_attn (scores + exact
// softmax + fused Wo + LN + FFN tail), one block per (b,i).
// R5: dc cached in LDS for pass-2 (kills serial global re-loads), __expf.

#define B_ 4
#define N_ 32
#define D_ 128
#define H_ 8
#define NC_ 27
#define DFF_ 512
#define L_ (NC_*N_)        // 864

// dual block-wide sum, blockDim = 128 (2 waves); result broadcast to all lanes
__device__ __forceinline__ void red2_block128(float& a, float& b, float* sbuf, int tid){
  for (int off = 32; off; off >>= 1){ a += __shfl_xor(a, off); b += __shfl_xor(b, off); }
  if ((tid & 63) == 0){ sbuf[(tid>>6)*2+0] = a; sbuf[(tid>>6)*2+1] = b; }
  __syncthreads();
  a = sbuf[0] + sbuf[2];
  b = sbuf[1] + sbuf[3];
  __syncthreads();   // safe reuse of sbuf
}

// dual block-wide sum, blockDim = 512 (8 waves), double-buffered by phase
__device__ __forceinline__ void bred2(float& a, float& b, float sred[2][8][2],
                                      int tid, int phase){
  for (int off = 32; off; off >>= 1){ a += __shfl_xor(a, off); b += __shfl_xor(b, off); }
  int pb = phase & 1;
  if ((tid & 63) == 0){ sred[pb][tid>>6][0] = a; sred[pb][tid>>6][1] = b; }
  __syncthreads();
  float sa = 0.f, sb = 0.f;
  #pragma unroll
  for (int w = 0; w < 8; w++){ sa += sred[pb][w][0]; sb += sred[pb][w][1]; }
  a = sa; b = sb;
}

// K1: blocks 0..127: per (b,n) row -> xh-derived quantities + Axk/Axv/q.
//     block 128: constants Gk/Gv/ek/ev/M6.
__global__ __launch_bounds__(128) void k_pre(
    const float* __restrict__ x, const float* __restrict__ Wp,
    const float* __restrict__ bp, const float* __restrict__ g1,
    const float* __restrict__ b1,
    const float* __restrict__ Wq, const float* __restrict__ bq,
    const float* __restrict__ Wk, const float* __restrict__ bk,
    const float* __restrict__ Wv, const float* __restrict__ bv,
    float* __restrict__ varx, float* __restrict__ dxp,
    float* __restrict__ Axk, float* __restrict__ Axv,
    float* __restrict__ qbuf,
    float* __restrict__ Gk, float* __restrict__ Gv,
    float* __restrict__ ekv, float* __restrict__ M6){
  __shared__ float sbuf[4];
  __shared__ float s1_[D_], s2_[D_], s3_[D_], s4_[D_];
  int blk = blockIdx.x, tid = threadIdx.x;
  float wp0 = Wp[tid], wp1 = Wp[D_+tid], wp2 = Wp[2*D_+tid];
  if (blk < 128){
    // ---- row path: r = b*32+n ----
    float t = x[blk*D_+tid] + bp[tid];
    float a = wp0, b = wp1;
    red2_block128(a, b, sbuf, tid);
    float m0 = a*(1.f/D_), m1 = b*(1.f/D_);
    float a2 = wp2, st = t;
    red2_block128(a2, st, sbuf, tid);
    float m2 = a2*(1.f/D_), mean = st*(1.f/D_);
    float xh = t - mean;
    float w0 = wp0-m0, w1 = wp1-m1, w2 = wp2-m2;
    float vv = xh*xh, d0 = xh*w0;
    red2_block128(vv, d0, sbuf, tid);
    float vx = vv*(1.f/D_);
    float d1 = xh*w1, d2 = xh*w2;
    red2_block128(d1, d2, sbuf, tid);
    s1_[tid] = xh*g1[tid];                                  // (xh*g1)
    s2_[tid] = xh*rsqrtf(vx+1e-5f)*g1[tid] + b1[tid];       // LN(x+bp) row
    __syncthreads();
    float axk = 0.f, axv = 0.f, qa = bq[tid];
    #pragma unroll 8
    for (int e=0;e<D_;e++){
      float u = s1_[e], h = s2_[e];
      axk += u*Wk[e*D_+tid];
      axv += u*Wv[e*D_+tid];
      qa  += h*Wq[e*D_+tid];
    }
    Axk[blk*D_+tid] = axk;
    Axv[blk*D_+tid] = axv;
    qbuf[blk*D_+tid] = qa;
    if (tid == 0){
      varx[blk] = vx;
      dxp[blk*3+0] = d0; dxp[blk*3+1] = d1; dxp[blk*3+2] = d2;
    }
  } else {
    // ---- consts path ----
    float a = wp0, b = wp1;
    red2_block128(a, b, sbuf, tid);
    float m0 = a*(1.f/D_), m1 = b*(1.f/D_);
    float a2 = wp2, dm = 0.f;
    red2_block128(a2, dm, sbuf, tid);
    float m2 = a2*(1.f/D_);
    float w0 = wp0-m0, w1 = wp1-m1, w2 = wp2-m2;
    float p0 = w0*w0, p1 = w0*w1;
    red2_block128(p0, p1, sbuf, tid);   // M00, M01
    float p2 = w0*w2, p3 = w1*w1;
    red2_block128(p2, p3, sbuf, tid);   // M02, M11
    float p4 = w1*w2, p5 = w2*w2;
    red2_block128(p4, p5, sbuf, tid);   // M12, M22
    float g = g1[tid];
    s1_[tid] = w0*g; s2_[tid] = w1*g; s3_[tid] = w2*g; s4_[tid] = b1[tid];
    __syncthreads();
    float gk0=0.f,gk1=0.f,gk2=0.f, gv0=0.f,gv1=0.f,gv2=0.f;
    float ek = bk[tid], ev = bv[tid];
    #pragma unroll 4
    for (int e=0;e<D_;e++){
      float wk = Wk[e*D_+tid], wv = Wv[e*D_+tid];
      gk0 += s1_[e]*wk; gk1 += s2_[e]*wk; gk2 += s3_[e]*wk;
      gv0 += s1_[e]*wv; gv1 += s2_[e]*wv; gv2 += s3_[e]*wv;
      ek  += s4_[e]*wk; ev  += s4_[e]*wv;
    }
    Gk[tid] = gk0; Gk[D_+tid] = gk1; Gk[2*D_+tid] = gk2;
    Gv[tid] = gv0; Gv[D_+tid] = gv1; Gv[2*D_+tid] = gv2;
    ekv[tid] = ek; ekv[D_+tid] = ev;
    if (tid == 0){ M6[0]=p0; M6[1]=p1; M6[2]=p2; M6[3]=p3; M6[4]=p4; M6[5]=p5; }
  }
}

// K2: one block per (b,i), 512 threads. Scores in LDS, exact 2-pass softmax
// (one wave per head), rank-3 V reconstruction, fused Wo + LN + FFN tail.
__global__ __launch_bounds__(512) void k_attn(
    const float* __restrict__ coords, const int* __restrict__ mask,
    const float* __restrict__ x, const float* __restrict__ bp,
    const float* __restrict__ varx, const float* __restrict__ dxp,
    const float* __restrict__ Axk, const float* __restrict__ Axv,
    const float* __restrict__ qbuf,
    const float* __restrict__ Gk, const float* __restrict__ Gv,
    const float* __restrict__ ekv, const float* __restrict__ M6,
    const float* __restrict__ Wo, const float* __restrict__ bo,
    const float* __restrict__ g2, const float* __restrict__ b2,
    const float* __restrict__ W1, const float* __restrict__ bf1,
    const float* __restrict__ W2, const float* __restrict__ bfb2,
    float* __restrict__ out){
  __shared__ float sc_s[H_*L_];      // 27648 B
  __shared__ float is_s[L_];
  __shared__ float dc_s[L_][3];      // relative coords, cached for pass 2
  __shared__ float cq_s[NC_][3];
  __shared__ float q_s[D_];
  __shared__ float qAxk_s[H_][N_];
  __shared__ float qGk_s[H_][3];
  __shared__ float S3_s[H_];
  __shared__ float varx_s[N_];
  __shared__ float dxp_s[N_][3];
  __shared__ int   mask_s[N_];
  __shared__ float Tnp_s[H_][2][N_];
  __shared__ float Sh_s[H_], RD_s[H_][3];
  __shared__ float M6_s[6];
  __shared__ float att_s[D_], y_s[D_], hn_s[D_], f_s[DFF_];
  __shared__ float po[4][D_];
  __shared__ float sred[2][8][2];
  int bi = blockIdx.x;               // b*32+i
  int b = bi >> 5, i = bi & 31;
  int tid = threadIdx.x;

  // ---- stage small per-(b,i) data ----
  if (tid < D_) q_s[tid] = qbuf[bi*D_+tid];
  if (tid < N_){ varx_s[tid] = varx[b*N_+tid]; mask_s[tid] = mask[b*N_+tid]; }
  if (tid >= 32 && tid < 128){
    int t2 = tid - 32;                       // 96 = 32 rows x 3
    dxp_s[t2/3][t2%3] = dxp[(b*N_ + t2/3)*3 + t2%3];
  }
  if (tid >= 128 && tid < 128+NC_*3){
    int t2 = tid - 128;                      // 81 = 27 images x 3 (query coords)
    cq_s[t2/3][t2%3] = coords[((size_t)(b*NC_ + t2/3)*N_ + i)*3 + t2%3];
  }
  if (tid >= 256 && tid < 262) M6_s[tid-256] = M6[tid-256];
  __syncthreads();

  // ---- q-derived constants ----
  if (tid < 256){
    int h = tid >> 5, n = tid & 31;
    float s = 0.f;
    #pragma unroll
    for (int k=0;k<16;k++) s += q_s[h*16+k]*Axk[(size_t)(b*N_+n)*D_ + h*16+k];
    qAxk_s[h][n] = s;
  } else if (tid < 256+24){
    int t2 = tid-256, h = t2/3, j = t2%3;
    float s = 0.f;
    #pragma unroll
    for (int k=0;k<16;k++) s += q_s[h*16+k]*Gk[j*D_ + h*16+k];
    qGk_s[h][j] = s;
  } else if (tid < 280+8){
    int h = tid-280;
    float s = 0.f;
    #pragma unroll
    for (int k=0;k<16;k++) s += q_s[h*16+k]*ekv[h*16+k];
    S3_s[h] = s;
  }
  __syncthreads();

  // ---- pass 1: inv_std + dc cache + 8 head scores per key l=(c,n) ----
  for (int l = tid; l < L_; l += 512){
    int c = l >> 5, n = l & 31;
    const float* ck = coords + ((size_t)(b*NC_+c)*N_ + n)*3;
    float d0 = ck[0]-cq_s[c][0], d1 = ck[1]-cq_s[c][1], d2 = ck[2]-cq_s[c][2];
    dc_s[l][0] = d0; dc_s[l][1] = d1; dc_s[l][2] = d2;
    float quad = d0*d0*M6_s[0] + d1*d1*M6_s[3] + d2*d2*M6_s[5]
               + 2.f*(d0*d1*M6_s[1] + d0*d2*M6_s[2] + d1*d2*M6_s[4]);
    float lin  = d0*dxp_s[n][0] + d1*dxp_s[n][1] + d2*dxp_s[n][2];
    float E = varx_s[n] + (quad + 2.f*lin)*(1.f/D_);
    float is = rsqrtf(fmaxf(E, 0.f) + 1e-5f);
    is_s[l] = is;
    bool mk = mask_s[n] != 0;
    #pragma unroll
    for (int h=0; h<H_; h++){
      float sc = 0.25f*(is*(qAxk_s[h][n]
                 + d0*qGk_s[h][0] + d1*qGk_s[h][1] + d2*qGk_s[h][2]) + S3_s[h]);
      sc_s[h*L_ + l] = mk ? sc : -1e9f;
    }
  }
  __syncthreads();

  // ---- pass 2: exact softmax, one wave per head (pure LDS) ----
  {
    int h = tid >> 6, lane = tid & 63, n = lane & 31, half = lane >> 5;
    int c0 = half ? 14 : 0, c1 = half ? NC_ : 14;
    float M = -3.0e38f;
    for (int c=c0; c<c1; c++) M = fmaxf(M, sc_s[h*L_ + c*N_ + n]);
    for (int off=32; off; off>>=1) M = fmaxf(M, __shfl_xor(M, off));
    float S=0.f, Tn=0.f, r0=0.f, r1=0.f, r2=0.f;
    for (int c=c0; c<c1; c++){
      int l = c*N_ + n;
      float w = __expf(sc_s[h*L_ + l] - M);
      float t = w * is_s[l];
      S += w; Tn += t;
      r0 += t*dc_s[l][0];
      r1 += t*dc_s[l][1];
      r2 += t*dc_s[l][2];
    }
    Tnp_s[h][half][n] = Tn;
    for (int off=32; off; off>>=1){
      S  += __shfl_xor(S,  off);
      r0 += __shfl_xor(r0, off);
      r1 += __shfl_xor(r1, off);
      r2 += __shfl_xor(r2, off);
    }
    if (lane == 0){ Sh_s[h]=S; RD_s[h][0]=r0; RD_s[h][1]=r1; RD_s[h][2]=r2; }
  }
  __syncthreads();

  // ---- attention output: rank-3 V reconstruction ----
  {
    int slot = tid >> 7, d = tid & 127, h = d >> 4;
    float pa = 0.f;
    #pragma unroll
    for (int n = slot*8; n < slot*8+8; n++){
      float Tn = Tnp_s[h][0][n] + Tnp_s[h][1][n];
      pa += Tn * Axv[(size_t)(b*N_+n)*D_ + d];
    }
    if (slot == 0)
      pa += RD_s[h][0]*Gv[d] + RD_s[h][1]*Gv[D_+d] + RD_s[h][2]*Gv[2*D_+d];
    po[slot][d] = pa;
  }
  __syncthreads();
  if (tid < D_){
    int h = tid >> 4;
    att_s[tid] = (po[0][tid]+po[1][tid]+po[2][tid]+po[3][tid])
                 / fmaxf(Sh_s[h], 1e-30f) + ekv[D_+tid];
  }
  __syncthreads();

  // ---- Wo + residual ----
  {
    int slot = tid >> 7, d = tid & 127;
    float a = 0.f;
    #pragma unroll 8
    for (int e=slot*32; e<slot*32+32; e++) a += att_s[e]*Wo[e*D_+d];
    po[slot][d] = a;
  }
  __syncthreads();
  float yv = 0.f;
  if (tid < D_){
    yv = x[bi*D_+tid] + bp[tid] + bo[tid]
       + po[0][tid]+po[1][tid]+po[2][tid]+po[3][tid];
    y_s[tid] = yv;
  }
  // ---- LN2 ----
  float s1 = (tid < D_) ? yv : 0.f, dm = 0.f;
  bred2(s1, dm, sred, tid, 0);
  float dev = yv - s1*(1.f/D_);
  float v1 = (tid < D_) ? dev*dev : 0.f; dm = 0.f;
  bred2(v1, dm, sred, tid, 1);
  if (tid < D_) hn_s[tid] = dev*rsqrtf(v1*(1.f/D_)+1e-5f)*g2[tid] + b2[tid];
  __syncthreads();
  // ---- FFN ----
  float f = bf1[tid];
  #pragma unroll 8
  for (int e=0;e<D_;e++) f += hn_s[e]*W1[e*DFF_+tid];
  f_s[tid] = fmaxf(f, 0.f);
  __syncthreads();
  {
    int slot = tid >> 7, d = tid & 127;
    float a = 0.f;
    #pragma unroll 8
    for (int j=slot*128; j<slot*128+128; j++) a += f_s[j]*W2[j*D_+d];
    po[slot][d] = a;
  }
  __syncthreads();
  if (tid < D_)
    out[bi*D_+tid] = y_s[tid] + bfb2[tid]
                   + po[0][tid]+po[1][tid]+po[2][tid]+po[3][tid];
}

extern "C" void kernel_launch(void* const* d_in, const int* in_sizes, int n_in,
                              void* d_out, int out_size, void* d_ws, size_t ws_size,
                              hipStream_t stream){
  const float* x      = (const float*)d_in[0];
  const int*   mask   = (const int*)  d_in[1];
  const float* coords = (const float*)d_in[2];
  const float* Wp     = (const float*)d_in[3];
  const float* bp     = (const float*)d_in[4];
  const float* Wq     = (const float*)d_in[5];
  const float* bq     = (const float*)d_in[6];
  const float* Wk     = (const float*)d_in[7];
  const float* bk     = (const float*)d_in[8];
  const float* Wv     = (const float*)d_in[9];
  const float* bv     = (const float*)d_in[10];
  const float* Wo     = (const float*)d_in[11];
  const float* bo     = (const float*)d_in[12];
  const float* g1     = (const float*)d_in[13];
  const float* b1     = (const float*)d_in[14];
  const float* g2     = (const float*)d_in[15];
  const float* b2     = (const float*)d_in[16];
  const float* W1     = (const float*)d_in[17];
  const float* bf1    = (const float*)d_in[18];
  const float* W2     = (const float*)d_in[19];
  const float* bfb2   = (const float*)d_in[20];

  // ws layout (fp32), ~200 KB total
  float* ws   = (float*)d_ws;
  float* varx = ws;                  // 128
  float* dxp  = varx + 128;          // 384
  float* M6   = dxp  + 384;          // 8
  float* Gk   = M6   + 8;            // 384
  float* Gv   = Gk   + 384;          // 384
  float* ekv  = Gv   + 384;          // 256
  float* Axk  = ekv  + 256;          // 16384
  float* Axv  = Axk  + 16384;        // 16384
  float* qbuf = Axv  + 16384;        // 16384

  k_pre <<<129, 128, 0, stream>>>(x, Wp, bp, g1, b1, Wq, bq, Wk, bk, Wv, bv,
                                  varx, dxp, Axk, Axv, qbuf, Gk, Gv, ekv, M6);
  k_attn<<<B_*N_, 512, 0, stream>>>(coords, mask, x, bp, varx, dxp, Axk, Axv,
                                    qbuf, Gk, Gv, ekv, M6, Wo, bo, g2, b2,
                                    W1, bf1, W2, bfb2, (float*)d_out);
}